// Round 2
// baseline (311.209 us; speedup 1.0000x reference)
//
#include <hip/hip_runtime.h>

#define N_NODES 50000
#define N_EDGES 400000
#define DIM 128
#define NA 32
#define NEG 0.01f

// ---------------- Kernel A: per-node projection ----------------
// proj[n][a]    = dot(x[n], W[a][0:128])      for a in [0,32)
// proj[n][32+a] = dot(x[n], W[a][128:256])    for a in [0,32)
// Block: 256 threads, 128 nodes (2 per lane). Wave w (0..3) computes
// proj-quarter [16w, 16w+16) for its 128 nodes.
__global__ __launch_bounds__(256) void proj_kernel(const float* __restrict__ x,
                                                   const float* __restrict__ W,
                                                   float* __restrict__ proj) {
    __shared__ float Wl[64 * 128];  // 32 KB: row a64 = concat-split W
    const int t = threadIdx.x;
    // Stage W into LDS, coalesced: Wl[a64*128 + k]
    for (int i = 0; i < 32; ++i) {
        int idx = i * 256 + t;
        int a = idx >> 7, k = idx & 127;
        Wl[idx] = (a < 32) ? W[a * 256 + k] : W[(a - 32) * 256 + 128 + k];
    }
    __syncthreads();

    const int n0 = blockIdx.x * 128 + (t & 63);
    const int n1 = n0 + 64;
    const int w = t >> 6;  // wave id -> proj quarter
    // clamp for loads (OOB lanes load node 0, stores are guarded)
    const int n0c = n0 < N_NODES ? n0 : 0;
    const int n1c = n1 < N_NODES ? n1 : 0;

    const float4* x4 = (const float4*)x;
    float acc0[16], acc1[16];
#pragma unroll
    for (int i = 0; i < 16; ++i) { acc0[i] = 0.f; acc1[i] = 0.f; }

#pragma unroll 1
    for (int kc = 0; kc < 32; ++kc) {
        float4 xv0 = x4[n0c * 32 + kc];
        float4 xv1 = x4[n1c * 32 + kc];
        const float* wbase = &Wl[(w * 16) * 128 + kc * 4];
#pragma unroll
        for (int i = 0; i < 16; ++i) {
            // broadcast LDS read (same address across wave)
            float4 wv = *(const float4*)(wbase + i * 128);
            acc0[i] += xv0.x * wv.x; acc1[i] += xv1.x * wv.x;
            acc0[i] += xv0.y * wv.y; acc1[i] += xv1.y * wv.y;
            acc0[i] += xv0.z * wv.z; acc1[i] += xv1.z * wv.z;
            acc0[i] += xv0.w * wv.w; acc1[i] += xv1.w * wv.w;
        }
    }

    float4* p4 = (float4*)proj;
    if (n0 < N_NODES) {
#pragma unroll
        for (int j = 0; j < 4; ++j)
            p4[n0 * 16 + w * 4 + j] =
                make_float4(acc0[4 * j], acc0[4 * j + 1], acc0[4 * j + 2], acc0[4 * j + 3]);
    }
    if (n1 < N_NODES) {
#pragma unroll
        for (int j = 0; j < 4; ++j)
            p4[n1 * 16 + w * 4 + j] =
                make_float4(acc1[4 * j], acc1[4 * j + 1], acc1[4 * j + 2], acc1[4 * j + 3]);
    }
}

// ---------------- Kernel B: per-edge softmax + PV ----------------
// Half-wave (32 lanes) per edge; wave handles an edge pair (2p, 2p+1).
// lane a: logit[a] = proj[s][a] + proj[d][32+a] + b_lin[a]
__global__ __launch_bounds__(256) void edge_kernel(const float* __restrict__ proj,
                                                   const int* __restrict__ ei,
                                                   const float* __restrict__ b_lin,
                                                   const float* __restrict__ anchor,
                                                   float* __restrict__ out,
                                                   int nwaves_total) {
    __shared__ float4 anc4[NA * 32];  // 16 KB, anchor[a][d] as float4 over d
    __shared__ float bl[4 * 64];      // per-wave softmax result staging

    const int t = threadIdx.x;
    {
        const float4* a4 = (const float4*)anchor;
        for (int i = t; i < NA * 32; i += 256) anc4[i] = a4[i];
    }
    __syncthreads();

    const int l = t & 63;      // lane in wave
    const int wv = t >> 6;     // wave in block
    const int a = l & 31;      // anchor index / softmax lane
    const int hh = l >> 5;     // which half-wave -> which edge of the pair
    const float bias = b_lin[a];
    const int wgid = blockIdx.x * 4 + wv;
    const int NP = N_EDGES / 2;

    for (int p = wgid; p < NP; p += nwaves_total) {
        const int e = 2 * p + hh;
        const int s = ei[e];
        const int d = ei[N_EDGES + e];
        // gather per-node projections (contiguous 128 B per half-wave)
        float lg = proj[s * 64 + a] + proj[d * 64 + 32 + a] + bias;
        lg = lg >= 0.f ? lg : NEG * lg;

        // softmax over 32 lanes of this half (xor masks < 32 stay in-half)
        float m = lg;
#pragma unroll
        for (int off = 16; off; off >>= 1) m = fmaxf(m, __shfl_xor(m, off, 64));
        float pe = __expf(lg - m);
        float sm = pe;
#pragma unroll
        for (int off = 16; off; off >>= 1) sm += __shfl_xor(sm, off, 64);
        float bv = pe / sm;

        // stage b through per-wave LDS so every lane can read all 32 values
        bl[wv * 64 + l] = bv;
        asm volatile("s_waitcnt lgkmcnt(0)" ::: "memory");

        // PV: prompt[dims 4a..4a+3] = sum_q b[q] * anchor[q][dims]
        float4 acc = make_float4(0.f, 0.f, 0.f, 0.f);
        const float4* blq = (const float4*)&bl[wv * 64 + hh * 32];
#pragma unroll
        for (int q = 0; q < 8; ++q) {
            float4 bq = blq[q];  // broadcast (2 addrs/wave, same-bank pair = free)
#pragma unroll
            for (int j = 0; j < 4; ++j) {
                const float bs = (j == 0) ? bq.x : (j == 1) ? bq.y : (j == 2) ? bq.z : bq.w;
                float4 an = anc4[(q * 4 + j) * 32 + a];
                acc.x += bs * an.x;
                acc.y += bs * an.y;
                acc.z += bs * an.z;
                acc.w += bs * an.w;
            }
        }
        // coalesced: full wave writes contiguous 1 KB (edges 2p and 2p+1)
        ((float4*)out)[e * 32 + a] = acc;
        asm volatile("" ::: "memory");
    }
}

extern "C" void kernel_launch(void* const* d_in, const int* in_sizes, int n_in,
                              void* d_out, int out_size, void* d_ws, size_t ws_size,
                              hipStream_t stream) {
    const float* x = (const float*)d_in[0];
    const int* ei = (const int*)d_in[1];
    // d_in[2] = layer (unused)
    const float* W = (const float*)d_in[3];
    const float* b_lin = (const float*)d_in[4];
    const float* anchor = (const float*)d_in[5];
    float* out = (float*)d_out;
    float* proj = (float*)d_ws;  // 50000*64*4 = 12.8 MB

    // Kernel A: 391 blocks x 128 nodes
    proj_kernel<<<(N_NODES + 127) / 128, 256, 0, stream>>>(x, W, proj);

    // Kernel B
    const int blocksB = 2048;
    edge_kernel<<<blocksB, 256, 0, stream>>>(proj, ei, b_lin, anchor, out, blocksB * 4);
}